// Round 7
// baseline (404.093 us; speedup 1.0000x reference)
//
#include <hip/hip_runtime.h>
#include <math.h>

typedef unsigned int u32;
typedef unsigned long long u64;
typedef _Float16 f16x8 __attribute__((ext_vector_type(8)));
typedef _Float16 f16x4 __attribute__((ext_vector_type(4)));
typedef float f32x16 __attribute__((ext_vector_type(16)));
typedef __attribute__((address_space(1))) const char gch;
typedef __attribute__((address_space(3))) char lch;

#define ZD 256      // z_dim (C)
#define KC 1024     // number of codes
#define TT 4096     // T
#define BB 16       // B
#define NROWS (BB*TT)     // 65536
#define TAU 0.30f         // margin: fp16 err (~0.06 @4.5sig) + u32-pack trunc (~0.18)
#define FLAGCAP 32768

__device__ __forceinline__ u32 umin32(u32 a, u32 b) { return a < b ? a : b; }
__device__ __forceinline__ u32 umax32(u32 a, u32 b) { return a > b ? a : b; }

// order-preserving float->u32 (flip), and inverse
__device__ __forceinline__ u32 flip32(float s) {
    int i = __float_as_int(s);
    return (u32)(i ^ ((i >> 31) | 0x80000000));
}
__device__ __forceinline__ float unflip32(u32 u) {
    int m = (~(((int)u) >> 31)) | 0x80000000;
    return __int_as_float((int)(u ^ (u32)m));
}

// ---------------- prep (blocks 0..255) + sparsity partials (blocks 256..383) ----------------
__global__ __launch_bounds__(256)
void vq_prep_sparsity(const float* __restrict__ emb, _Float16* __restrict__ eh,
                      float* __restrict__ re, float* __restrict__ hist,
                      int* __restrict__ cnt, float* __restrict__ scal,
                      float* __restrict__ spar) {
    __shared__ __align__(16) float er[8][260];
    __shared__ float wmax[8][4];
    __shared__ float wsum[8][4];
    __shared__ float shD[8];

    const int tid = threadIdx.x;
    if (blockIdx.x < 256) {
        // ---- prep: zero hist/cnt/scal, re=||e||^2, emb->fp16 ----
        int gid = blockIdx.x * 256 + tid;
        if (gid < KC) hist[gid] = 0.f;
        if (gid < 4)  scal[gid] = 0.f;
        if (gid == 0) cnt[0] = 0;

        int code = gid >> 6;   // one wave per code
        int lane = tid & 63;
        float4 v = *(const float4*)(emb + (size_t)code * ZD + lane * 4);
        float s = v.x*v.x + v.y*v.y + v.z*v.z + v.w*v.w;
        #pragma unroll
        for (int off = 32; off; off >>= 1) s += __shfl_down(s, off, 64);
        if (lane == 0) re[code] = s;

        f16x4 hv;
        hv[0] = (_Float16)v.x; hv[1] = (_Float16)v.y;
        hv[2] = (_Float16)v.z; hv[3] = (_Float16)v.w;
        *(f16x4*)(eh + (size_t)code * ZD + lane * 4) = hv;
        return;
    }

    // ---- sparsity: 8 rows/block, partial to spar[bid2] ----
    const int bid2 = blockIdx.x - 256;      // 0..127
    const int w    = tid >> 6;
    const int lane = tid & 63;
    const int r0   = bid2 * 8;

    for (int i = tid; i < 8 * 256; i += 256) er[i >> 8][i & 255] = emb[(size_t)r0 * ZD + i];
    __syncthreads();

    float dots[4][8];   // [cc][r]
    #pragma unroll
    for (int cc = 0; cc < 4; ++cc) {
        const int c = cc * 256 + tid;
        const float4* ec = (const float4*)(emb + (size_t)c * ZD);
        float a[8] = {0.f,0.f,0.f,0.f,0.f,0.f,0.f,0.f};
        for (int k4 = 0; k4 < ZD / 4; ++k4) {
            float4 e4 = ec[k4];
            #pragma unroll
            for (int r = 0; r < 8; ++r) {
                const float* a4 = &er[r][k4 * 4];
                a[r] = fmaf(e4.x, a4[0], fmaf(e4.y, a4[1],
                       fmaf(e4.z, a4[2], fmaf(e4.w, a4[3], a[r]))));
            }
        }
        #pragma unroll
        for (int r = 0; r < 8; ++r) dots[cc][r] = a[r];
        const int gr = c - r0;
        if (gr >= 0 && gr < 8) shD[gr] = a[gr];
    }

    #pragma unroll
    for (int r = 0; r < 8; ++r) {
        float m = fmaxf(fmaxf(dots[0][r], dots[1][r]), fmaxf(dots[2][r], dots[3][r]));
        #pragma unroll
        for (int off = 32; off; off >>= 1) m = fmaxf(m, __shfl_xor(m, off, 64));
        if (lane == 0) wmax[r][w] = m;
    }
    __syncthreads();
    #pragma unroll
    for (int r = 0; r < 8; ++r) {
        const float M = fmaxf(fmaxf(wmax[r][0], wmax[r][1]), fmaxf(wmax[r][2], wmax[r][3]));
        float se = expf(dots[0][r] - M) + expf(dots[1][r] - M)
                 + expf(dots[2][r] - M) + expf(dots[3][r] - M);
        #pragma unroll
        for (int off = 32; off; off >>= 1) se += __shfl_xor(se, off, 64);
        if (lane == 0) wsum[r][w] = se;
    }
    __syncthreads();
    if (tid == 0) {
        float acc = 0.f;
        #pragma unroll
        for (int r = 0; r < 8; ++r) {
            const float M = fmaxf(fmaxf(wmax[r][0], wmax[r][1]), fmaxf(wmax[r][2], wmax[r][3]));
            const float S = wsum[r][0] + wsum[r][1] + wsum[r][2] + wsum[r][3];
            acc += M + logf(S) - shD[r];
        }
        spar[bid2] = acc;
    }
}

// ---- stage one 64-code tile (32KB) via global_load_lds, pre-swizzled source (8 waves) ----
__device__ __forceinline__ void stage_tile8(const char* ehc, char* dstbase,
                                            int tile, int w, int l) {
    const int srow = tile * 32768;          // 64 codes * 512B
    #pragma unroll
    for (int j = 0; j < 4; ++j) {
        const int gi  = w * 4 + j;          // 0..31
        const int c   = 2 * gi + (l >> 5);  // local code this lane's 16B lands in
        const int kbs = (l & 31) * 16;
        const int off = srow + c * 512 + (kbs ^ ((c & 7) << 4));
        __builtin_amdgcn_global_load_lds((gch*)(ehc + off),
                                         (lch*)(dstbase + gi * 1024), 16, 0, 0);
    }
}

// ---------------- fused argmin (32x32x16 MFMA) + out-write + loss + hist ----------------
// 512 blocks x 512 threads. Block: 128 rows. Wave (wr=w&3, wc=w>>2):
// rows [32wr,32wr+32), code-half wc of each 64-code tile. 16 tiles, dbuf LDS.
__global__ __launch_bounds__(512, 4)
void vq_argmin_mfma(const float* __restrict__ z, const _Float16* __restrict__ eh,
                    const float* __restrict__ emb, const float* __restrict__ re,
                    float* __restrict__ out, float* __restrict__ scal,
                    float* __restrict__ hist, int* __restrict__ cnt,
                    int* __restrict__ flags) {
    __shared__ __align__(16) char lds[73216];
    float* reL   = (float*)(lds + 65536);       // 1024 f32
    float* zsqL  = (float*)(lds + 69632);       // 128 f32
    u32*   redv1 = (u32*)  (lds + 70144);       // [2][128]
    u32*   redv2 = (u32*)  (lds + 71168);       // [2][128]
    int*   idsL  = (int*)  (lds + 72192);       // 128
    float* lossL = (float*)(lds + 72704);       // 128

    const int tid = threadIdx.x;
    const int w   = tid >> 6;       // 0..7
    const int l   = tid & 63;
    const int wr  = w & 3;          // row group
    const int wc  = w >> 2;         // code half
    const int c31 = l & 31;
    const int hw  = l >> 5;
    const int r0  = blockIdx.x * 128;
    const int b   = r0 >> 12;
    const int t0  = r0 & 4095;
    const char* ehc = (const char*)eh;

    if (tid < 256) *(float4*)(reL + tid * 4) = *(const float4*)(re + tid * 4);

    // z A-fragments: 32 rows/wave; lane: row=c31, k = ks*16 + hw*8 + j. Exact ||z||^2.
    f16x8 ah[16];
    float zsq = 0.f;
    {
        const float* zr = z + (size_t)b * ZD * TT + t0 + wr * 32 + c31;
        #pragma unroll
        for (int ks = 0; ks < 16; ++ks) {
            f16x8 h;
            #pragma unroll
            for (int j = 0; j < 8; ++j) {
                float v = zr[(size_t)(ks * 16 + hw * 8 + j) * TT];
                zsq = fmaf(v, v, zsq);
                h[j] = (_Float16)v;
            }
            ah[ks] = h;
        }
    }
    zsq += __shfl_xor(zsq, 32, 64);
    if (l < 32 && wc == 0) zsqL[wr * 32 + l] = zsq;

    u32 v1[16], v2[16];
    #pragma unroll
    for (int r = 0; r < 16; ++r) { v1[r] = 0xFFFFFFFFu; v2[r] = 0xFFFFFFFFu; }

    asm volatile("s_waitcnt vmcnt(0) lgkmcnt(0)" ::: "memory");
    stage_tile8(ehc, lds, 0, w, l);

    const int cb = wc * 32 + c31;       // local code 0..63
    const u32 sw = (u32)((cb & 7) << 4);

    #pragma unroll 2
    for (int t = 0; t < 16; ++t) {
        const int cur = t & 1;
        asm volatile("s_waitcnt vmcnt(0)" ::: "memory");   // stage(t) landed
        __builtin_amdgcn_sched_barrier(0);
        __builtin_amdgcn_s_barrier();   // all staged; all done reading buf[cur^1]
        if (t < 15) stage_tile8(ehc, lds + ((cur ^ 1) << 15), t + 1, w, l);

        const char* hb = lds + (cur << 15) + cb * 512;
        f32x16 a = {0.f,0.f,0.f,0.f,0.f,0.f,0.f,0.f,0.f,0.f,0.f,0.f,0.f,0.f,0.f,0.f};
        __builtin_amdgcn_s_setprio(1);
        #pragma unroll
        for (int ks = 0; ks < 16; ++ks) {
            f16x8 bf = *(const f16x8*)(hb + (((u32)(ks * 32 + hw * 16)) ^ sw));
            a = __builtin_amdgcn_mfma_f32_32x32x16_f16(ah[ks], bf, a, 0, 0, 0);
        }
        __builtin_amdgcn_s_setprio(0);

        const int code = t * 64 + cb;
        const float rc = reL[code];
        #pragma unroll
        for (int r = 0; r < 16; ++r) {
            float s = fmaf(-2.f, a[r], rc);
            u32 p = (flip32(s) & 0xFFFFFC00u) | (u32)code;
            u32 n2 = umin32(v2[r], umax32(v1[r], p));
            v1[r] = umin32(v1[r], p);
            v2[r] = n2;
        }
    }

    // reduce across 32 lanes (code dim); lanes l and l^{1..16} share rows
    #pragma unroll
    for (int off = 1; off < 32; off <<= 1) {
        #pragma unroll
        for (int r = 0; r < 16; ++r) {
            u32 o1 = (u32)__shfl_xor((int)v1[r], off, 64);
            u32 o2 = (u32)__shfl_xor((int)v2[r], off, 64);
            u32 n2 = umin32(umax32(v1[r], o1), umin32(v2[r], o2));
            v1[r] = umin32(v1[r], o1);
            v2[r] = n2;
        }
    }
    if (c31 == 0) {
        #pragma unroll
        for (int r = 0; r < 16; ++r) {
            // C layout (m74): row = (reg&3) + 8*(reg>>2) + 4*hw
            const int rowl = wr * 32 + (r & 3) + 8 * (r >> 2) + 4 * hw;
            redv1[wc * 128 + rowl] = v1[r];
            redv2[wc * 128 + rowl] = v2[r];
        }
    }
    __syncthreads();

    // merge code-halves; emit idx/loss/hist/flags (one thread per row)
    if (tid < 128) {
        const u32 a1 = redv1[tid], b1 = redv1[128 + tid];
        const u32 a2 = redv2[tid], b2 = redv2[128 + tid];
        const u32 m1 = umin32(a1, b1);
        const u32 m2 = umin32(umax32(a1, b1), umin32(a2, b2));
        const int code = (int)(m1 & 1023u);
        const float s1 = unflip32(m1 & 0xFFFFFC00u);
        const float s2 = unflip32(m2 & 0xFFFFFC00u);
        const bool fl = (s2 - s1) < TAU;
        idsL[tid] = code;
        lossL[tid] = fl ? zsqL[tid] : (zsqL[tid] + s1);   // fixup adds exact s for flagged
        atomicAdd(&hist[code], 1.0f);
        if (fl) {
            int p = atomicAdd(cnt, 1);
            if (p < FLAGCAP) flags[p] = (r0 + tid) | (code << 16);
        }
    }
    __syncthreads();

    // block loss reduce (threads 0..127)
    if (tid < 128) {
        float lv = lossL[tid];
        #pragma unroll
        for (int off = 32; off; off >>= 1) lv += __shfl_down(lv, off, 64);
        if (l == 0) { atomicAdd(scal + 0, lv); atomicAdd(scal + 1, lv); }
    }

    // out-write: wave w covers c in [32w, 32w+32), all 128 rows
    {
        const int c0 = w * 32;
        float* ob = out + (size_t)b * ZD * TT + t0;
        #pragma unroll
        for (int half = 0; half < 2; ++half) {
            const int tt = half * 64 + l;
            const int ii = idsL[tt];
            const float4* er4 = (const float4*)(emb + (size_t)ii * ZD + c0);
            #pragma unroll
            for (int c4 = 0; c4 < 8; ++c4) {
                float4 ev = er4[c4];
                float* o0 = ob + (size_t)(c0 + c4 * 4) * TT + tt;
                o0[0]      = ev.x;
                o0[TT]     = ev.y;
                o0[2 * TT] = ev.z;
                o0[3 * TT] = ev.w;
            }
        }
    }
}

// ---------------- exact fp32 rescore, 8 flagged rows per pass ----------------
__global__ __launch_bounds__(256)
void vq_fixup_kernel(const float* __restrict__ z, const float* __restrict__ emb,
                     const float* __restrict__ re, const int* __restrict__ cnt,
                     const int* __restrict__ flags, float* __restrict__ out,
                     float* __restrict__ scal, float* __restrict__ hist) {
    __shared__ __align__(16) float zs[8][ZD];
    __shared__ u64 sb[4][8];
    __shared__ int nwS[8];
    __shared__ float addS;
    const int tid = threadIdx.x;
    const int w   = tid >> 6;
    const int lane = tid & 63;
    int n = *cnt;
    if (n > FLAGCAP) n = FLAGCAP;

    for (int base = blockIdx.x * 8; base < n; base += gridDim.x * 8) {
        const int nr = (n - base < 8) ? (n - base) : 8;
        __syncthreads();
        for (int i = tid; i < nr * 256; i += 256) {
            const int r = i >> 8, k = i & 255;
            const int rowg = flags[base + r] & 0xFFFF;
            zs[r][k] = z[(size_t)(rowg >> 12) * ZD * TT + (size_t)k * TT + (rowg & 4095)];
        }
        __syncthreads();

        u64 best[8];
        #pragma unroll
        for (int r = 0; r < 8; ++r) best[r] = 0xFFFFFFFFFFFFFFFFull;

        for (int cc = 0; cc < 4; ++cc) {
            const int c = cc * 256 + tid;
            const float4* ec = (const float4*)(emb + (size_t)c * ZD);
            float a[8] = {0.f,0.f,0.f,0.f,0.f,0.f,0.f,0.f};
            for (int k4 = 0; k4 < ZD / 4; ++k4) {
                float4 e4 = ec[k4];
                #pragma unroll
                for (int r = 0; r < 8; ++r) {
                    const float* a4 = &zs[r][k4 * 4];
                    a[r] = fmaf(e4.x, a4[0], fmaf(e4.y, a4[1],
                           fmaf(e4.z, a4[2], fmaf(e4.w, a4[3], a[r]))));
                }
            }
            const float rc = re[c];
            #pragma unroll
            for (int r = 0; r < 8; ++r) {
                if (r < nr) {
                    float s = fmaf(-2.f, a[r], rc);
                    u64 pk = ((u64)flip32(s) << 32) | (u32)c;
                    if (pk < best[r]) best[r] = pk;
                }
            }
        }
        // exact reduce: wave then cross-wave
        #pragma unroll
        for (int r = 0; r < 8; ++r) {
            if (r < nr) {
                u64 bv = best[r];
                #pragma unroll
                for (int off = 32; off; off >>= 1) {
                    u64 o = (u64)__shfl_xor((long long)bv, off, 64);
                    if (o < bv) bv = o;
                }
                if (lane == 0) sb[w][r] = bv;
            }
        }
        __syncthreads();
        if (tid == 0) addS = 0.f;
        __syncthreads();
        if (tid < nr) {
            u64 m = sb[0][tid];
            if (sb[1][tid] < m) m = sb[1][tid];
            if (sb[2][tid] < m) m = sb[2][tid];
            if (sb[3][tid] < m) m = sb[3][tid];
            const int nc  = (int)(u32)(m & 0xFFFFFFFFull);
            const float s = unflip32((u32)(m >> 32));
            const int old = (flags[base + tid] >> 16) & 1023;
            atomicAdd(&addS, s);
            if (nc != old) {
                atomicAdd(&hist[old], -1.0f);
                atomicAdd(&hist[nc], 1.0f);
                nwS[tid] = nc;
            } else nwS[tid] = -1;
        }
        __syncthreads();
        if (tid == 0) { atomicAdd(scal + 0, addS); atomicAdd(scal + 1, addS); }
        for (int r = 0; r < nr; ++r) {
            const int nw = nwS[r];
            if (nw >= 0) {
                const int rowg = flags[base + r] & 0xFFFF;
                out[(size_t)(rowg >> 12) * ZD * TT + (size_t)tid * TT + (rowg & 4095)]
                    = emb[(size_t)nw * ZD + tid];
            }
        }
    }
}

// ---------------- final: perplexity + sparsity partial sum ----------------
__global__ __launch_bounds__(256)
void vq_final_kernel(const float* __restrict__ hist, const float* __restrict__ spar,
                     float* __restrict__ scal) {
    __shared__ float red[256];
    const int tid = threadIdx.x;
    float s = 0.f;
    for (int j = tid; j < KC; j += 256) {
        float p = hist[j] * (1.0f / (float)NROWS);
        s -= p * logf(p + 1e-10f);
    }
    red[tid] = s;
    __syncthreads();
    for (int st = 128; st; st >>= 1) {
        if (tid < st) red[tid] += red[tid + st];
        __syncthreads();
    }
    if (tid == 0) scal[2] = expf(red[0]);
    __syncthreads();
    red[tid] = (tid < 128) ? spar[tid] : 0.f;
    __syncthreads();
    for (int st = 128; st; st >>= 1) {
        if (tid < st) red[tid] += red[tid + st];
        __syncthreads();
    }
    if (tid == 0) scal[3] = red[0] * (1.0f / (float)KC);
}

extern "C" void kernel_launch(void* const* d_in, const int* in_sizes, int n_in,
                              void* d_out, int out_size, void* d_ws, size_t ws_size,
                              hipStream_t stream) {
    const float* z   = (const float*)d_in[0];
    const float* emb = (const float*)d_in[1];
    float* out = (float*)d_out;
    const size_t NOUT = (size_t)BB * ZD * TT;    // 16777216
    float* scal = out + NOUT;                    // [qut, enc, perp, sparsity]

    float* re    = (float*)d_ws;                 // 1024 f32
    float* hist  = re + KC;                      // 1024 f32
    int*   cnt   = (int*)(hist + KC);            // 4 i32
    int*   flags = cnt + 4;                      // FLAGCAP i32
    float* spar  = (float*)(flags + FLAGCAP);    // 128 f32
    _Float16* eh = (_Float16*)(spar + 128);      // 1024*256 f16

    vq_prep_sparsity<<<384, 256, 0, stream>>>(emb, eh, re, hist, cnt, scal, spar);
    vq_argmin_mfma<<<NROWS / 128, 512, 0, stream>>>(z, eh, emb, re, out, scal, hist, cnt, flags);
    vq_fixup_kernel<<<128, 256, 0, stream>>>(z, emb, re, cnt, flags, out, scal, hist);
    vq_final_kernel<<<1, 256, 0, stream>>>(hist, spar, scal);
}

// Round 8
// 247.671 us; speedup vs baseline: 1.6316x; 1.6316x over previous
//
#include <hip/hip_runtime.h>
#include <math.h>

typedef unsigned int u32;
typedef unsigned long long u64;
typedef _Float16 f16x8 __attribute__((ext_vector_type(8)));
typedef _Float16 f16x4 __attribute__((ext_vector_type(4)));
typedef float f32x4 __attribute__((ext_vector_type(4)));
typedef __attribute__((address_space(1))) const char gch;
typedef __attribute__((address_space(3))) char lch;

#define ZD 256      // z_dim (C)
#define KC 1024     // number of codes
#define TT 4096     // T
#define BB 16       // B
#define NROWS (BB*TT)     // 65536
#define TAU 0.12f         // margin threshold (~6 sigma of fp16 pairwise err)
#define FLAGCAP 32768

__device__ __forceinline__ u32 flip32(float s) {
    int i = __float_as_int(s);
    return (u32)(i ^ ((i >> 31) | 0x80000000));
}
__device__ __forceinline__ float unflip32(u32 u) {
    int m = (~(((int)u) >> 31)) | 0x80000000;
    return __int_as_float((int)(u ^ (u32)m));
}

// ---------------- prep (blocks 0..255) + sparsity partials (blocks 256..383) ----------------
__global__ __launch_bounds__(256)
void vq_prep_sparsity(const float* __restrict__ emb, _Float16* __restrict__ eh,
                      float* __restrict__ re, float* __restrict__ hist,
                      int* __restrict__ cnt, float* __restrict__ scal,
                      float* __restrict__ spar) {
    __shared__ __align__(16) float er[8][260];
    __shared__ float wmax[8][4];
    __shared__ float wsum[8][4];
    __shared__ float shD[8];

    const int tid = threadIdx.x;
    if (blockIdx.x < 256) {
        // ---- prep: zero hist/cnt/scal, re=||e||^2, emb->fp16 ----
        int gid = blockIdx.x * 256 + tid;
        if (gid < KC) hist[gid] = 0.f;
        if (gid < 4)  scal[gid] = 0.f;
        if (gid == 0) cnt[0] = 0;

        int code = gid >> 6;   // one wave per code
        int lane = tid & 63;
        float4 v = *(const float4*)(emb + (size_t)code * ZD + lane * 4);
        float s = v.x*v.x + v.y*v.y + v.z*v.z + v.w*v.w;
        #pragma unroll
        for (int off = 32; off; off >>= 1) s += __shfl_down(s, off, 64);
        if (lane == 0) re[code] = s;

        f16x4 hv;
        hv[0] = (_Float16)v.x; hv[1] = (_Float16)v.y;
        hv[2] = (_Float16)v.z; hv[3] = (_Float16)v.w;
        *(f16x4*)(eh + (size_t)code * ZD + lane * 4) = hv;
        return;
    }

    // ---- sparsity: 8 rows/block, partial to spar[bid2] ----
    const int bid2 = blockIdx.x - 256;      // 0..127
    const int w    = tid >> 6;
    const int lane = tid & 63;
    const int r0   = bid2 * 8;

    for (int i = tid; i < 8 * 256; i += 256) er[i >> 8][i & 255] = emb[(size_t)r0 * ZD + i];
    __syncthreads();

    float dots[4][8];   // [cc][r]
    #pragma unroll
    for (int cc = 0; cc < 4; ++cc) {
        const int c = cc * 256 + tid;
        const float4* ec = (const float4*)(emb + (size_t)c * ZD);
        float a[8] = {0.f,0.f,0.f,0.f,0.f,0.f,0.f,0.f};
        for (int k4 = 0; k4 < ZD / 4; ++k4) {
            float4 e4 = ec[k4];
            #pragma unroll
            for (int r = 0; r < 8; ++r) {
                const float* a4 = &er[r][k4 * 4];
                a[r] = fmaf(e4.x, a4[0], fmaf(e4.y, a4[1],
                       fmaf(e4.z, a4[2], fmaf(e4.w, a4[3], a[r]))));
            }
        }
        #pragma unroll
        for (int r = 0; r < 8; ++r) dots[cc][r] = a[r];
        const int gr = c - r0;
        if (gr >= 0 && gr < 8) shD[gr] = a[gr];
    }

    #pragma unroll
    for (int r = 0; r < 8; ++r) {
        float m = fmaxf(fmaxf(dots[0][r], dots[1][r]), fmaxf(dots[2][r], dots[3][r]));
        #pragma unroll
        for (int off = 32; off; off >>= 1) m = fmaxf(m, __shfl_xor(m, off, 64));
        if (lane == 0) wmax[r][w] = m;
    }
    __syncthreads();
    #pragma unroll
    for (int r = 0; r < 8; ++r) {
        const float M = fmaxf(fmaxf(wmax[r][0], wmax[r][1]), fmaxf(wmax[r][2], wmax[r][3]));
        float se = expf(dots[0][r] - M) + expf(dots[1][r] - M)
                 + expf(dots[2][r] - M) + expf(dots[3][r] - M);
        #pragma unroll
        for (int off = 32; off; off >>= 1) se += __shfl_xor(se, off, 64);
        if (lane == 0) wsum[r][w] = se;
    }
    __syncthreads();
    if (tid == 0) {
        float acc = 0.f;
        #pragma unroll
        for (int r = 0; r < 8; ++r) {
            const float M = fmaxf(fmaxf(wmax[r][0], wmax[r][1]), fmaxf(wmax[r][2], wmax[r][3]));
            const float S = wsum[r][0] + wsum[r][1] + wsum[r][2] + wsum[r][3];
            acc += M + logf(S) - shD[r];
        }
        spar[bid2] = acc;
    }
}

// ---- stage one 64-code tile (32KB) via global_load_lds, pre-swizzled source (8 waves) ----
__device__ __forceinline__ void stage_tile8(const char* ehc, char* dstbase,
                                            int tile, int w, int l) {
    const int srow = tile * 32768;          // 64 codes * 512B
    #pragma unroll
    for (int j = 0; j < 4; ++j) {
        const int gi  = w * 4 + j;          // 0..31
        const int c   = 2 * gi + (l >> 5);  // local code this lane's 16B lands in
        const int kbs = (l & 31) * 16;
        const int off = srow + c * 512 + (kbs ^ ((c & 7) << 4));
        __builtin_amdgcn_global_load_lds((gch*)(ehc + off),
                                         (lch*)(dstbase + gi * 1024), 16, 0, 0);
    }
}

// ---------------- fused argmin + out-write + loss + hist (r6 known-good structure) ----------------
// 512 blocks x 512 threads (8 waves). Block: 128 rows; wave w: rows [16w,16w+16).
// 16 tiles x 64 codes, double-buffered LDS, 1 barrier/tile, 4 waves/SIMD.
__global__ __launch_bounds__(512, 4)
void vq_argmin_mfma(const float* __restrict__ z, const _Float16* __restrict__ eh,
                    const float* __restrict__ emb, const float* __restrict__ re,
                    float* __restrict__ out, float* __restrict__ scal,
                    float* __restrict__ hist, int* __restrict__ cnt,
                    int* __restrict__ flags) {
    __shared__ __align__(16) char lds[71168];
    float* reL   = (float*)(lds + 65536);   // 1024 f32
    float* zsqL  = (float*)(lds + 69632);   // 128 f32
    int*   idsL  = (int*)  (lds + 70144);   // 128 i32
    float* lossL = (float*)(lds + 70656);   // 128 f32

    const int tid = threadIdx.x;
    const int w   = tid >> 6;       // 0..7
    const int l   = tid & 63;
    const int lane15 = l & 15;
    const int lk     = l >> 4;
    const int r0  = blockIdx.x * 128;
    const int b   = r0 >> 12;
    const int t0  = r0 & 4095;
    const char* ehc = (const char*)eh;

    if (tid < 256) *(float4*)(reL + tid * 4) = *(const float4*)(re + tid * 4);

    // z A-fragments (16 rows/wave): row = lane15, k-quarter = lk; also exact ||z||^2
    f16x8 ah[8];
    float zsq = 0.f;
    {
        const float* zr = z + (size_t)b * ZD * TT + t0 + w * 16 + lane15;
        #pragma unroll
        for (int ks = 0; ks < 8; ++ks) {
            f16x8 h;
            #pragma unroll
            for (int j = 0; j < 8; ++j) {
                float v = zr[(size_t)(ks * 32 + lk * 8 + j) * TT];
                zsq = fmaf(v, v, zsq);
                h[j] = (_Float16)v;
            }
            ah[ks] = h;
        }
    }
    zsq += __shfl_xor(zsq, 16, 64);
    zsq += __shfl_xor(zsq, 32, 64);
    if (l < 16) zsqL[w * 16 + lane15] = zsq;

    float v1[4], v2[4];
    int   i1[4];
    #pragma unroll
    for (int r = 0; r < 4; ++r) { v1[r] = 3.4e38f; v2[r] = 3.4e38f; i1[r] = 0; }

    asm volatile("s_waitcnt vmcnt(0) lgkmcnt(0)" ::: "memory");
    stage_tile8(ehc, lds, 0, w, l);

    for (int t = 0; t < 16; ++t) {
        const int cur = t & 1;
        asm volatile("s_waitcnt vmcnt(0)" ::: "memory");   // stage(t) landed
        __builtin_amdgcn_sched_barrier(0);
        __builtin_amdgcn_s_barrier();   // all staged; all done reading buf[cur^1]
        if (t < 15) stage_tile8(ehc, lds + ((cur ^ 1) << 15), t + 1, w, l);

        const char* hb = lds + (cur << 15);
        #pragma unroll
        for (int cg = 0; cg < 4; ++cg) {
            const int c  = cg * 16 + lane15;        // local code 0..63
            const int sw = (c & 7) << 4;
            f16x8 bh[8];
            #pragma unroll
            for (int ks = 0; ks < 8; ++ks)
                bh[ks] = *(const f16x8*)(hb + c * 512 + ((lk * 16 + ks * 64) ^ sw));

            f32x4 a = {0.f, 0.f, 0.f, 0.f};
            __builtin_amdgcn_s_setprio(1);
            #pragma unroll
            for (int ks = 0; ks < 8; ++ks)
                a = __builtin_amdgcn_mfma_f32_16x16x32_f16(ah[ks], bh[ks], a, 0, 0, 0);
            __builtin_amdgcn_s_setprio(0);

            const int codeg = t * 64 + cg * 16 + lane15;
            const float rc = reL[codeg];
            #pragma unroll
            for (int r = 0; r < 4; ++r) {
                float s0 = fmaf(-2.f, a[r], rc);
                if (s0 < v1[r]) { v2[r] = v1[r]; v1[r] = s0; i1[r] = codeg; }
                else if (s0 < v2[r]) v2[r] = s0;
            }
        }
    }

    // reduce across the 16 lanes holding different codes (same rows)
    #pragma unroll
    for (int off = 1; off < 16; off <<= 1) {
        #pragma unroll
        for (int r = 0; r < 4; ++r) {
            float ov1 = __shfl_xor(v1[r], off, 64);
            int   oi1 = __shfl_xor(i1[r], off, 64);
            float ov2 = __shfl_xor(v2[r], off, 64);
            float nv2 = fminf(fmaxf(v1[r], ov1), fminf(v2[r], ov2));
            if (ov1 < v1[r] || (ov1 == v1[r] && oi1 < i1[r])) { v1[r] = ov1; i1[r] = oi1; }
            v2[r] = nv2;
        }
    }
    if (lane15 == 0) {
        #pragma unroll
        for (int r = 0; r < 4; ++r) {
            const int row = w * 16 + lk * 4 + r;    // local row 0..127
            idsL[row] = i1[r];
            const bool fl = (v2[r] - v1[r] < TAU);
            // always include exact zsq; fixup adds the exact (re - 2 dot) for flagged rows
            lossL[row] = fl ? zsqL[row] : (zsqL[row] + v1[r]);
            atomicAdd(&hist[i1[r]], 1.0f);
            if (fl) {
                int p = atomicAdd(cnt, 1);
                if (p < FLAGCAP) flags[p] = (r0 + row) | (i1[r] << 16);
            }
        }
    }
    __syncthreads();

    // block loss reduce (threads 0..127)
    if (tid < 128) {
        float lv = lossL[tid];
        #pragma unroll
        for (int off = 32; off; off >>= 1) lv += __shfl_down(lv, off, 64);
        if (l == 0) { atomicAdd(scal + 0, lv); atomicAdd(scal + 1, lv); }
    }

    // out-write: wave w covers c in [32w, 32w+32), all 128 rows
    {
        const int c0 = w * 32;
        float* ob = out + (size_t)b * ZD * TT + t0;
        #pragma unroll
        for (int half = 0; half < 2; ++half) {
            const int tt = half * 64 + l;
            const int ii = idsL[tt];
            const float4* er4 = (const float4*)(emb + (size_t)ii * ZD + c0);
            #pragma unroll
            for (int c4 = 0; c4 < 8; ++c4) {
                float4 ev = er4[c4];
                float* o0 = ob + (size_t)(c0 + c4 * 4) * TT + tt;
                o0[0]      = ev.x;
                o0[TT]     = ev.y;
                o0[2 * TT] = ev.z;
                o0[3 * TT] = ev.w;
            }
        }
    }
}

// ---------------- exact fp32 rescore, 8 flagged rows per pass ----------------
__global__ __launch_bounds__(256)
void vq_fixup_kernel(const float* __restrict__ z, const float* __restrict__ emb,
                     const float* __restrict__ re, const int* __restrict__ cnt,
                     const int* __restrict__ flags, float* __restrict__ out,
                     float* __restrict__ scal, float* __restrict__ hist) {
    __shared__ __align__(16) float zs[8][ZD];
    __shared__ u64 sb[4][8];
    __shared__ int nwS[8];
    __shared__ float addS;
    const int tid = threadIdx.x;
    const int w   = tid >> 6;
    const int lane = tid & 63;
    int n = *cnt;
    if (n > FLAGCAP) n = FLAGCAP;

    for (int base = blockIdx.x * 8; base < n; base += gridDim.x * 8) {
        const int nr = (n - base < 8) ? (n - base) : 8;
        __syncthreads();
        for (int i = tid; i < nr * 256; i += 256) {
            const int r = i >> 8, k = i & 255;
            const int rowg = flags[base + r] & 0xFFFF;
            zs[r][k] = z[(size_t)(rowg >> 12) * ZD * TT + (size_t)k * TT + (rowg & 4095)];
        }
        __syncthreads();

        u64 best[8];
        #pragma unroll
        for (int r = 0; r < 8; ++r) best[r] = 0xFFFFFFFFFFFFFFFFull;

        for (int cc = 0; cc < 4; ++cc) {
            const int c = cc * 256 + tid;
            const float4* ec = (const float4*)(emb + (size_t)c * ZD);
            float a[8] = {0.f,0.f,0.f,0.f,0.f,0.f,0.f,0.f};
            for (int k4 = 0; k4 < ZD / 4; ++k4) {
                float4 e4 = ec[k4];
                #pragma unroll
                for (int r = 0; r < 8; ++r) {
                    const float* a4 = &zs[r][k4 * 4];
                    a[r] = fmaf(e4.x, a4[0], fmaf(e4.y, a4[1],
                           fmaf(e4.z, a4[2], fmaf(e4.w, a4[3], a[r]))));
                }
            }
            const float rc = re[c];
            #pragma unroll
            for (int r = 0; r < 8; ++r) {
                if (r < nr) {
                    float s = fmaf(-2.f, a[r], rc);
                    u64 pk = ((u64)flip32(s) << 32) | (u32)c;
                    if (pk < best[r]) best[r] = pk;
                }
            }
        }
        // exact reduce: wave then cross-wave
        #pragma unroll
        for (int r = 0; r < 8; ++r) {
            if (r < nr) {
                u64 bv = best[r];
                #pragma unroll
                for (int off = 32; off; off >>= 1) {
                    u64 o = (u64)__shfl_xor((long long)bv, off, 64);
                    if (o < bv) bv = o;
                }
                if (lane == 0) sb[w][r] = bv;
            }
        }
        __syncthreads();
        if (tid == 0) addS = 0.f;
        __syncthreads();
        if (tid < nr) {
            u64 m = sb[0][tid];
            if (sb[1][tid] < m) m = sb[1][tid];
            if (sb[2][tid] < m) m = sb[2][tid];
            if (sb[3][tid] < m) m = sb[3][tid];
            const int nc  = (int)(u32)(m & 0xFFFFFFFFull);
            const float s = unflip32((u32)(m >> 32));
            const int old = (flags[base + tid] >> 16) & 1023;
            atomicAdd(&addS, s);
            if (nc != old) {
                atomicAdd(&hist[old], -1.0f);
                atomicAdd(&hist[nc], 1.0f);
                nwS[tid] = nc;
            } else nwS[tid] = -1;
        }
        __syncthreads();
        if (tid == 0) { atomicAdd(scal + 0, addS); atomicAdd(scal + 1, addS); }
        for (int r = 0; r < nr; ++r) {
            const int nw = nwS[r];
            if (nw >= 0) {
                const int rowg = flags[base + r] & 0xFFFF;
                out[(size_t)(rowg >> 12) * ZD * TT + (size_t)tid * TT + (rowg & 4095)]
                    = emb[(size_t)nw * ZD + tid];
            }
        }
    }
}

// ---------------- final: perplexity + sparsity partial sum ----------------
__global__ __launch_bounds__(256)
void vq_final_kernel(const float* __restrict__ hist, const float* __restrict__ spar,
                     float* __restrict__ scal) {
    __shared__ float red[256];
    const int tid = threadIdx.x;
    float s = 0.f;
    for (int j = tid; j < KC; j += 256) {
        float p = hist[j] * (1.0f / (float)NROWS);
        s -= p * logf(p + 1e-10f);
    }
    red[tid] = s;
    __syncthreads();
    for (int st = 128; st; st >>= 1) {
        if (tid < st) red[tid] += red[tid + st];
        __syncthreads();
    }
    if (tid == 0) scal[2] = expf(red[0]);
    __syncthreads();
    red[tid] = (tid < 128) ? spar[tid] : 0.f;
    __syncthreads();
    for (int st = 128; st; st >>= 1) {
        if (tid < st) red[tid] += red[tid + st];
        __syncthreads();
    }
    if (tid == 0) scal[3] = red[0] * (1.0f / (float)KC);
}

extern "C" void kernel_launch(void* const* d_in, const int* in_sizes, int n_in,
                              void* d_out, int out_size, void* d_ws, size_t ws_size,
                              hipStream_t stream) {
    const float* z   = (const float*)d_in[0];
    const float* emb = (const float*)d_in[1];
    float* out = (float*)d_out;
    const size_t NOUT = (size_t)BB * ZD * TT;    // 16777216
    float* scal = out + NOUT;                    // [qut, enc, perp, sparsity]

    float* re    = (float*)d_ws;                 // 1024 f32
    float* hist  = re + KC;                      // 1024 f32
    int*   cnt   = (int*)(hist + KC);            // 4 i32
    int*   flags = cnt + 4;                      // FLAGCAP i32
    float* spar  = (float*)(flags + FLAGCAP);    // 128 f32
    _Float16* eh = (_Float16*)(spar + 128);      // 1024*256 f16

    vq_prep_sparsity<<<384, 256, 0, stream>>>(emb, eh, re, hist, cnt, scal, spar);
    vq_argmin_mfma<<<NROWS / 128, 512, 0, stream>>>(z, eh, emb, re, out, scal, hist, cnt, flags);
    vq_fixup_kernel<<<128, 256, 0, stream>>>(z, emb, re, cnt, flags, out, scal, hist);
    vq_final_kernel<<<1, 256, 0, stream>>>(hist, spar, scal);
}

// Round 9
// 221.264 us; speedup vs baseline: 1.8263x; 1.1193x over previous
//
#include <hip/hip_runtime.h>
#include <math.h>

typedef unsigned int u32;
typedef unsigned long long u64;
typedef _Float16 f16x8 __attribute__((ext_vector_type(8)));
typedef _Float16 f16x4 __attribute__((ext_vector_type(4)));
typedef float f32x4 __attribute__((ext_vector_type(4)));
typedef __attribute__((address_space(1))) const char gch;
typedef __attribute__((address_space(3))) char lch;

#define ZD 256      // z_dim (C)
#define KC 1024     // number of codes
#define TT 4096     // T
#define BB 16       // B
#define NROWS (BB*TT)     // 65536
#define TAU 0.12f         // margin threshold (~6 sigma of fp16 pairwise err)
#define FLAGCAP 32768

__device__ __forceinline__ u32 flip32(float s) {
    int i = __float_as_int(s);
    return (u32)(i ^ ((i >> 31) | 0x80000000));
}
__device__ __forceinline__ float unflip32(u32 u) {
    int m = (~(((int)u) >> 31)) | 0x80000000;
    return __int_as_float((int)(u ^ (u32)m));
}

// ---------------- prep: zero hist/cnt/scal, re=||e||^2, emb->fp16 ----------------
__global__ __launch_bounds__(256)
void vq_prep_kernel(const float* __restrict__ emb, _Float16* __restrict__ eh,
                    float* __restrict__ re, float* __restrict__ hist,
                    int* __restrict__ cnt, float* __restrict__ scal) {
    int gid = blockIdx.x * 256 + threadIdx.x;
    if (gid < KC) hist[gid] = 0.f;
    if (gid < 4)  scal[gid] = 0.f;
    if (gid == 0) cnt[0] = 0;

    int code = gid >> 6;   // one wave per code
    int lane = threadIdx.x & 63;
    float4 v = *(const float4*)(emb + (size_t)code * ZD + lane * 4);
    float s = v.x*v.x + v.y*v.y + v.z*v.z + v.w*v.w;
    #pragma unroll
    for (int off = 32; off; off >>= 1) s += __shfl_down(s, off, 64);
    if (lane == 0) re[code] = s;

    f16x4 hv;
    hv[0] = (_Float16)v.x; hv[1] = (_Float16)v.y;
    hv[2] = (_Float16)v.z; hv[3] = (_Float16)v.w;
    *(f16x4*)(eh + (size_t)code * ZD + lane * 4) = hv;
}

// ---- stage one 32-code half-tile (16KB) via global_load_lds, pre-swizzled source ----
__device__ __forceinline__ void stage_half(const char* ehc, char* dstbase,
                                           int h, int w, int l) {
    const int srow = h * 16384;             // 32 codes * 512B
    #pragma unroll
    for (int j = 0; j < 2; ++j) {
        const int gi  = w * 2 + j;          // 0..15
        const int c   = 2 * gi + (l >> 5);  // local code this lane's 16B lands in
        const int kbs = (l & 31) * 16;
        const int off = srow + c * 512 + (kbs ^ ((c & 7) << 4));
        __builtin_amdgcn_global_load_lds((gch*)(ehc + off),
                                         (lch*)(dstbase + gi * 1024), 16, 0, 0);
    }
}

// ---- one 32-code compute phase: 16 ds_read_b128 + 16 MFMA + min-update ----
__device__ __forceinline__ void compute_phase(const char* hb, int h,
                                              const f16x8 (&ah)[8], const float* reL,
                                              float (&v1)[4], float (&v2)[4], int (&i1)[4],
                                              int lane15, int lk) {
    #pragma unroll
    for (int cg = 0; cg < 2; ++cg) {
        const int c  = cg * 16 + lane15;        // local code 0..31
        const int sw = (c & 7) << 4;
        f16x8 bh[8];
        #pragma unroll
        for (int ks = 0; ks < 8; ++ks)
            bh[ks] = *(const f16x8*)(hb + c * 512 + ((lk * 16 + ks * 64) ^ sw));

        f32x4 a = {0.f, 0.f, 0.f, 0.f};
        __builtin_amdgcn_s_setprio(1);
        #pragma unroll
        for (int ks = 0; ks < 8; ++ks)
            a = __builtin_amdgcn_mfma_f32_16x16x32_f16(ah[ks], bh[ks], a, 0, 0, 0);
        __builtin_amdgcn_s_setprio(0);

        const int codeg = h * 32 + c;
        const float rc = reL[codeg];
        #pragma unroll
        for (int r = 0; r < 4; ++r) {
            float s0 = fmaf(-2.f, a[r], rc);
            if (s0 < v1[r]) { v2[r] = v1[r]; v1[r] = s0; i1[r] = codeg; }
            else if (s0 < v2[r]) v2[r] = s0;
        }
    }
}

// ---------------- fused argmin (blocks 0..511) + sparsity (blocks 512..639) ----------------
// argmin: 512 threads, 128 rows/block, wave w: rows [16w,16w+16).
// 32 half-tile phases x 32 codes, ring-4 LDS, counted vmcnt(4) (T3/T4), 1 barrier/phase.
__global__ __launch_bounds__(512, 4)
void vq_argmin_mfma(const float* __restrict__ z, const _Float16* __restrict__ eh,
                    const float* __restrict__ emb, const float* __restrict__ re,
                    float* __restrict__ out, float* __restrict__ scal,
                    float* __restrict__ hist, int* __restrict__ cnt,
                    int* __restrict__ flags, float* __restrict__ spar) {
    __shared__ __align__(16) char lds[71168];   // ring 4x16KB | reL 4KB | tails

    const int tid = threadIdx.x;

    // ================= sparsity path (blocks 512..639) =================
    if (blockIdx.x >= 512) {
        float* er    = (float*)lds;             // [8][260]
        float* wmaxS = (float*)(lds + 8320);    // [8][8]
        float* wsumS = wmaxS + 64;              // [8][8]
        float* shD   = wsumS + 64;              // [8]
        const int bid2 = blockIdx.x - 512;      // 0..127
        const int r0s  = bid2 * 8;
        const int wv = tid >> 6, lane = tid & 63;

        for (int i = tid; i < 8 * 256; i += 512)
            er[(i >> 8) * 260 + (i & 255)] = emb[(size_t)r0s * ZD + i];
        __syncthreads();

        float dots[2][8];
        #pragma unroll
        for (int cc = 0; cc < 2; ++cc) {
            const int c = cc * 512 + tid;
            const float4* ec = (const float4*)(emb + (size_t)c * ZD);
            float a[8] = {0.f,0.f,0.f,0.f,0.f,0.f,0.f,0.f};
            for (int k4 = 0; k4 < ZD / 4; ++k4) {
                float4 e4 = ec[k4];
                #pragma unroll
                for (int r = 0; r < 8; ++r) {
                    const float* a4 = &er[r * 260 + k4 * 4];
                    a[r] = fmaf(e4.x, a4[0], fmaf(e4.y, a4[1],
                           fmaf(e4.z, a4[2], fmaf(e4.w, a4[3], a[r]))));
                }
            }
            #pragma unroll
            for (int r = 0; r < 8; ++r) dots[cc][r] = a[r];
            const int gr = c - r0s;
            if (gr >= 0 && gr < 8) shD[gr] = a[gr];
        }
        #pragma unroll
        for (int r = 0; r < 8; ++r) {
            float m = fmaxf(dots[0][r], dots[1][r]);
            #pragma unroll
            for (int off = 32; off; off >>= 1) m = fmaxf(m, __shfl_xor(m, off, 64));
            if (lane == 0) wmaxS[r * 8 + wv] = m;
        }
        __syncthreads();
        #pragma unroll
        for (int r = 0; r < 8; ++r) {
            float M = wmaxS[r * 8];
            #pragma unroll
            for (int j = 1; j < 8; ++j) M = fmaxf(M, wmaxS[r * 8 + j]);
            float se = expf(dots[0][r] - M) + expf(dots[1][r] - M);
            #pragma unroll
            for (int off = 32; off; off >>= 1) se += __shfl_xor(se, off, 64);
            if (lane == 0) wsumS[r * 8 + wv] = se;
        }
        __syncthreads();
        if (tid == 0) {
            float acc = 0.f;
            #pragma unroll
            for (int r = 0; r < 8; ++r) {
                float M = wmaxS[r * 8];
                #pragma unroll
                for (int j = 1; j < 8; ++j) M = fmaxf(M, wmaxS[r * 8 + j]);
                float S = 0.f;
                #pragma unroll
                for (int j = 0; j < 8; ++j) S += wsumS[r * 8 + j];
                acc += M + logf(S) - shD[r];
            }
            spar[bid2] = acc;
        }
        return;
    }

    // ================= argmin path (blocks 0..511) =================
    float* reL   = (float*)(lds + 65536);   // 1024 f32
    float* zsqL  = (float*)(lds + 69632);   // 128 f32
    int*   idsL  = (int*)  (lds + 70144);   // 128 i32
    float* lossL = (float*)(lds + 70656);   // 128 f32

    const int w   = tid >> 6;       // 0..7
    const int l   = tid & 63;
    const int lane15 = l & 15;
    const int lk     = l >> 4;
    const int r0  = blockIdx.x * 128;
    const int b   = r0 >> 12;
    const int t0  = r0 & 4095;
    const char* ehc = (const char*)eh;

    if (tid < 256) *(float4*)(reL + tid * 4) = *(const float4*)(re + tid * 4);

    // z A-fragments (16 rows/wave): row = lane15, k-quarter = lk; also exact ||z||^2
    f16x8 ah[8];
    float zsq = 0.f;
    {
        const float* zr = z + (size_t)b * ZD * TT + t0 + w * 16 + lane15;
        #pragma unroll
        for (int ks = 0; ks < 8; ++ks) {
            f16x8 h;
            #pragma unroll
            for (int j = 0; j < 8; ++j) {
                float v = zr[(size_t)(ks * 32 + lk * 8 + j) * TT];
                zsq = fmaf(v, v, zsq);
                h[j] = (_Float16)v;
            }
            ah[ks] = h;
        }
    }
    zsq += __shfl_xor(zsq, 16, 64);
    zsq += __shfl_xor(zsq, 32, 64);
    if (l < 16) zsqL[w * 16 + lane15] = zsq;

    float v1[4], v2[4];
    int   i1[4];
    #pragma unroll
    for (int r = 0; r < 4; ++r) { v1[r] = 3.4e38f; v2[r] = 3.4e38f; i1[r] = 0; }

    // drain A-loads + reL ds_write so vmcnt counts only stage loads
    asm volatile("s_waitcnt vmcnt(0) lgkmcnt(0)" ::: "memory");
    stage_half(ehc, lds,         0, w, l);
    stage_half(ehc, lds + 16384, 1, w, l);
    stage_half(ehc, lds + 32768, 2, w, l);

    // Main pipeline: phase h reads buf[h&3]; stage(h+3) (issued after the phase-h
    // barrier) writes buf[(h+3)&3] == buf[(h-1)&3], whose reads finished at that
    // barrier. vmcnt(4): with stages 0..h+2 issued (2 loads each), <=4 outstanding
    // means stages 0..h have landed (own pieces); barrier covers all waves.
    for (int h = 0; h < 30; ++h) {
        asm volatile("s_waitcnt vmcnt(4)" ::: "memory");
        __builtin_amdgcn_sched_barrier(0);
        __builtin_amdgcn_s_barrier();
        if (h < 29) stage_half(ehc, lds + ((h + 3) & 3) * 16384, h + 3, w, l);
        compute_phase(lds + (h & 3) * 16384, h, ah, reL, v1, v2, i1, lane15, lk);
    }
    asm volatile("s_waitcnt vmcnt(2)" ::: "memory");
    __builtin_amdgcn_sched_barrier(0);
    __builtin_amdgcn_s_barrier();
    compute_phase(lds + (30 & 3) * 16384, 30, ah, reL, v1, v2, i1, lane15, lk);
    asm volatile("s_waitcnt vmcnt(0)" ::: "memory");
    __builtin_amdgcn_sched_barrier(0);
    __builtin_amdgcn_s_barrier();
    compute_phase(lds + (31 & 3) * 16384, 31, ah, reL, v1, v2, i1, lane15, lk);

    // reduce across the 16 lanes holding different codes (same rows)
    #pragma unroll
    for (int off = 1; off < 16; off <<= 1) {
        #pragma unroll
        for (int r = 0; r < 4; ++r) {
            float ov1 = __shfl_xor(v1[r], off, 64);
            int   oi1 = __shfl_xor(i1[r], off, 64);
            float ov2 = __shfl_xor(v2[r], off, 64);
            float nv2 = fminf(fmaxf(v1[r], ov1), fminf(v2[r], ov2));
            if (ov1 < v1[r] || (ov1 == v1[r] && oi1 < i1[r])) { v1[r] = ov1; i1[r] = oi1; }
            v2[r] = nv2;
        }
    }
    if (lane15 == 0) {
        #pragma unroll
        for (int r = 0; r < 4; ++r) {
            const int row = w * 16 + lk * 4 + r;    // local row 0..127
            idsL[row] = i1[r];
            const bool fl = (v2[r] - v1[r] < TAU);
            lossL[row] = fl ? zsqL[row] : (zsqL[row] + v1[r]);
            atomicAdd(&hist[i1[r]], 1.0f);
            if (fl) {
                int p = atomicAdd(cnt, 1);
                if (p < FLAGCAP) flags[p] = (r0 + row) | (i1[r] << 16);
            }
        }
    }
    __syncthreads();

    // block loss reduce (threads 0..127)
    if (tid < 128) {
        float lv = lossL[tid];
        #pragma unroll
        for (int off = 32; off; off >>= 1) lv += __shfl_down(lv, off, 64);
        if (l == 0) { atomicAdd(scal + 0, lv); atomicAdd(scal + 1, lv); }
    }

    // out-write: wave w covers c in [32w, 32w+32), all 128 rows
    {
        const int c0 = w * 32;
        float* ob = out + (size_t)b * ZD * TT + t0;
        #pragma unroll
        for (int half = 0; half < 2; ++half) {
            const int tt = half * 64 + l;
            const int ii = idsL[tt];
            const float4* er4 = (const float4*)(emb + (size_t)ii * ZD + c0);
            #pragma unroll
            for (int c4 = 0; c4 < 8; ++c4) {
                float4 ev = er4[c4];
                float* o0 = ob + (size_t)(c0 + c4 * 4) * TT + tt;
                o0[0]      = ev.x;
                o0[TT]     = ev.y;
                o0[2 * TT] = ev.z;
                o0[3 * TT] = ev.w;
            }
        }
    }
}

// ---------------- exact fp32 rescore, 8 flagged rows per pass ----------------
__global__ __launch_bounds__(256)
void vq_fixup_kernel(const float* __restrict__ z, const float* __restrict__ emb,
                     const float* __restrict__ re, const int* __restrict__ cnt,
                     const int* __restrict__ flags, float* __restrict__ out,
                     float* __restrict__ scal, float* __restrict__ hist) {
    __shared__ __align__(16) float zs[8][ZD];
    __shared__ u64 sb[4][8];
    __shared__ int nwS[8];
    __shared__ float addS;
    const int tid = threadIdx.x;
    const int w   = tid >> 6;
    const int lane = tid & 63;
    int n = *cnt;
    if (n > FLAGCAP) n = FLAGCAP;

    for (int base = blockIdx.x * 8; base < n; base += gridDim.x * 8) {
        const int nr = (n - base < 8) ? (n - base) : 8;
        __syncthreads();
        for (int i = tid; i < nr * 256; i += 256) {
            const int r = i >> 8, k = i & 255;
            const int rowg = flags[base + r] & 0xFFFF;
            zs[r][k] = z[(size_t)(rowg >> 12) * ZD * TT + (size_t)k * TT + (rowg & 4095)];
        }
        __syncthreads();

        u64 best[8];
        #pragma unroll
        for (int r = 0; r < 8; ++r) best[r] = 0xFFFFFFFFFFFFFFFFull;

        for (int cc = 0; cc < 4; ++cc) {
            const int c = cc * 256 + tid;
            const float4* ec = (const float4*)(emb + (size_t)c * ZD);
            float a[8] = {0.f,0.f,0.f,0.f,0.f,0.f,0.f,0.f};
            for (int k4 = 0; k4 < ZD / 4; ++k4) {
                float4 e4 = ec[k4];
                #pragma unroll
                for (int r = 0; r < 8; ++r) {
                    const float* a4 = &zs[r][k4 * 4];
                    a[r] = fmaf(e4.x, a4[0], fmaf(e4.y, a4[1],
                           fmaf(e4.z, a4[2], fmaf(e4.w, a4[3], a[r]))));
                }
            }
            const float rc = re[c];
            #pragma unroll
            for (int r = 0; r < 8; ++r) {
                if (r < nr) {
                    float s = fmaf(-2.f, a[r], rc);
                    u64 pk = ((u64)flip32(s) << 32) | (u32)c;
                    if (pk < best[r]) best[r] = pk;
                }
            }
        }
        #pragma unroll
        for (int r = 0; r < 8; ++r) {
            if (r < nr) {
                u64 bv = best[r];
                #pragma unroll
                for (int off = 32; off; off >>= 1) {
                    u64 o = (u64)__shfl_xor((long long)bv, off, 64);
                    if (o < bv) bv = o;
                }
                if (lane == 0) sb[w][r] = bv;
            }
        }
        __syncthreads();
        if (tid == 0) addS = 0.f;
        __syncthreads();
        if (tid < nr) {
            u64 m = sb[0][tid];
            if (sb[1][tid] < m) m = sb[1][tid];
            if (sb[2][tid] < m) m = sb[2][tid];
            if (sb[3][tid] < m) m = sb[3][tid];
            const int nc  = (int)(u32)(m & 0xFFFFFFFFull);
            const float s = unflip32((u32)(m >> 32));
            const int old = (flags[base + tid] >> 16) & 1023;
            atomicAdd(&addS, s);
            if (nc != old) {
                atomicAdd(&hist[old], -1.0f);
                atomicAdd(&hist[nc], 1.0f);
                nwS[tid] = nc;
            } else nwS[tid] = -1;
        }
        __syncthreads();
        if (tid == 0) { atomicAdd(scal + 0, addS); atomicAdd(scal + 1, addS); }
        for (int r = 0; r < nr; ++r) {
            const int nw = nwS[r];
            if (nw >= 0) {
                const int rowg = flags[base + r] & 0xFFFF;
                out[(size_t)(rowg >> 12) * ZD * TT + (size_t)tid * TT + (rowg & 4095)]
                    = emb[(size_t)nw * ZD + tid];
            }
        }
    }
}

// ---------------- final: perplexity + sparsity partial sum ----------------
__global__ __launch_bounds__(256)
void vq_final_kernel(const float* __restrict__ hist, const float* __restrict__ spar,
                     float* __restrict__ scal) {
    __shared__ float red[256];
    const int tid = threadIdx.x;
    float s = 0.f;
    for (int j = tid; j < KC; j += 256) {
        float p = hist[j] * (1.0f / (float)NROWS);
        s -= p * logf(p + 1e-10f);
    }
    red[tid] = s;
    __syncthreads();
    for (int st = 128; st; st >>= 1) {
        if (tid < st) red[tid] += red[tid + st];
        __syncthreads();
    }
    if (tid == 0) scal[2] = expf(red[0]);
    __syncthreads();
    red[tid] = (tid < 128) ? spar[tid] : 0.f;
    __syncthreads();
    for (int st = 128; st; st >>= 1) {
        if (tid < st) red[tid] += red[tid + st];
        __syncthreads();
    }
    if (tid == 0) scal[3] = red[0] * (1.0f / (float)KC);
}

extern "C" void kernel_launch(void* const* d_in, const int* in_sizes, int n_in,
                              void* d_out, int out_size, void* d_ws, size_t ws_size,
                              hipStream_t stream) {
    const float* z   = (const float*)d_in[0];
    const float* emb = (const float*)d_in[1];
    float* out = (float*)d_out;
    const size_t NOUT = (size_t)BB * ZD * TT;    // 16777216
    float* scal = out + NOUT;                    // [qut, enc, perp, sparsity]

    float* re    = (float*)d_ws;                 // 1024 f32
    float* hist  = re + KC;                      // 1024 f32
    int*   cnt   = (int*)(hist + KC);            // 4 i32
    int*   flags = cnt + 4;                      // FLAGCAP i32
    float* spar  = (float*)(flags + FLAGCAP);    // 128 f32
    _Float16* eh = (_Float16*)(spar + 128);      // 1024*256 f16

    vq_prep_kernel<<<256, 256, 0, stream>>>(emb, eh, re, hist, cnt, scal);
    vq_argmin_mfma<<<512 + 128, 512, 0, stream>>>(z, eh, emb, re, out, scal, hist,
                                                  cnt, flags, spar);
    vq_fixup_kernel<<<256, 256, 0, stream>>>(z, emb, re, cnt, flags, out, scal, hist);
    vq_final_kernel<<<1, 256, 0, stream>>>(hist, spar, scal);
}

// Round 10
// 190.552 us; speedup vs baseline: 2.1207x; 1.1612x over previous
//
#include <hip/hip_runtime.h>
#include <math.h>

typedef unsigned int u32;
typedef unsigned long long u64;
typedef _Float16 f16x8 __attribute__((ext_vector_type(8)));
typedef _Float16 f16x4 __attribute__((ext_vector_type(4)));
typedef float f32x4 __attribute__((ext_vector_type(4)));
typedef __attribute__((address_space(1))) const char gch;
typedef __attribute__((address_space(3))) char lch;

#define ZD 256      // z_dim (C)
#define KC 1024     // number of codes
#define TT 4096     // T
#define BB 16       // B
#define NROWS (BB*TT)     // 65536
#define TAU 0.12f         // margin threshold (~6 sigma of fp16 pairwise err)
#define FLAGCAP 32768

__device__ __forceinline__ u32 flip32(float s) {
    int i = __float_as_int(s);
    return (u32)(i ^ ((i >> 31) | 0x80000000));
}
__device__ __forceinline__ float unflip32(u32 u) {
    int m = (~(((int)u) >> 31)) | 0x80000000;
    return __int_as_float((int)(u ^ (u32)m));
}

// ---------------- prep: zero hist/cnt/scal, re=||e||^2, emb->fp16 ----------------
__global__ __launch_bounds__(256)
void vq_prep_kernel(const float* __restrict__ emb, _Float16* __restrict__ eh,
                    float* __restrict__ re, float* __restrict__ hist,
                    int* __restrict__ cnt, float* __restrict__ scal) {
    int gid = blockIdx.x * 256 + threadIdx.x;
    if (gid < KC) hist[gid] = 0.f;
    if (gid < 4)  scal[gid] = 0.f;
    if (gid == 0) cnt[0] = 0;

    int code = gid >> 6;   // one wave per code
    int lane = threadIdx.x & 63;
    float4 v = *(const float4*)(emb + (size_t)code * ZD + lane * 4);
    float s = v.x*v.x + v.y*v.y + v.z*v.z + v.w*v.w;
    #pragma unroll
    for (int off = 32; off; off >>= 1) s += __shfl_down(s, off, 64);
    if (lane == 0) re[code] = s;

    f16x4 hv;
    hv[0] = (_Float16)v.x; hv[1] = (_Float16)v.y;
    hv[2] = (_Float16)v.z; hv[3] = (_Float16)v.w;
    *(f16x4*)(eh + (size_t)code * ZD + lane * 4) = hv;
}

// ---- stage one 32-code half-tile (16KB) via global_load_lds; 4 waves x 4 loads ----
__device__ __forceinline__ void stage_half4(const char* ehc, char* dstbase,
                                            int h, int w, int l) {
    const int srow = h * 16384;             // 32 codes * 512B
    #pragma unroll
    for (int j = 0; j < 4; ++j) {
        const int gi  = w * 4 + j;          // 0..15
        const int c   = 2 * gi + (l >> 5);  // local code this lane's 16B lands in
        const int kbs = (l & 31) * 16;
        const int off = srow + c * 512 + (kbs ^ ((c & 7) << 4));
        __builtin_amdgcn_global_load_lds((gch*)(ehc + off),
                                         (lch*)(dstbase + gi * 1024), 16, 0, 0);
    }
}

// ---- one 32-code compute phase: 16 ds_read_b128 + 32 MFMA (2 rowgroups) ----
__device__ __forceinline__ void compute_phase32(const char* hb, int h,
                                                const f16x8 (&ah)[2][8], const float* reL,
                                                float (&v1)[8], float (&v2)[8], int (&i1)[8],
                                                int lane15, int lk) {
    #pragma unroll
    for (int cg = 0; cg < 2; ++cg) {
        const int c  = cg * 16 + lane15;        // local code 0..31
        const int sw = (lane15 & 7) << 4;       // c&7 == lane15&7
        f16x8 bh[8];
        #pragma unroll
        for (int ks = 0; ks < 8; ++ks)
            bh[ks] = *(const f16x8*)(hb + c * 512 + ((lk * 16 + ks * 64) ^ sw));

        f32x4 a0 = {0.f, 0.f, 0.f, 0.f};
        f32x4 a1 = {0.f, 0.f, 0.f, 0.f};
        __builtin_amdgcn_s_setprio(1);
        #pragma unroll
        for (int ks = 0; ks < 8; ++ks) {
            a0 = __builtin_amdgcn_mfma_f32_16x16x32_f16(ah[0][ks], bh[ks], a0, 0, 0, 0);
            a1 = __builtin_amdgcn_mfma_f32_16x16x32_f16(ah[1][ks], bh[ks], a1, 0, 0, 0);
        }
        __builtin_amdgcn_s_setprio(0);

        const int codeg = h * 32 + c;
        const float rc = reL[codeg];
        #pragma unroll
        for (int r = 0; r < 4; ++r) {
            // branchless top-2: v2 = med3(v1, v2, s); i1 = s<v1 ? code : i1; v1 = min
            float s0 = fmaf(-2.f, a0[r], rc);
            float n2a = fminf(fmaxf(v1[r], s0), v2[r]);          // med3(v1,v2,s0)
            i1[r] = (s0 < v1[r]) ? codeg : i1[r];
            v1[r] = fminf(v1[r], s0);
            v2[r] = n2a;
            float s1 = fmaf(-2.f, a1[r], rc);
            float n2b = fminf(fmaxf(v1[4 + r], s1), v2[4 + r]);
            i1[4 + r] = (s1 < v1[4 + r]) ? codeg : i1[4 + r];
            v1[4 + r] = fminf(v1[4 + r], s1);
            v2[4 + r] = n2b;
        }
    }
}

// ---------------- fused argmin + out-write + loss + hist ----------------
// 512 blocks x 256 threads (4 waves). Block: 128 rows; wave w: rows [32w,32w+32).
// 32 half-tile phases x 32 codes, ring-4 LDS, counted vmcnt(8) (T3/T4), 1 barrier/phase.
__global__ __launch_bounds__(256, 2)
void vq_argmin_mfma(const float* __restrict__ z, const _Float16* __restrict__ eh,
                    const float* __restrict__ emb, const float* __restrict__ re,
                    float* __restrict__ out, float* __restrict__ scal,
                    float* __restrict__ hist, int* __restrict__ cnt,
                    int* __restrict__ flags) {
    __shared__ __align__(16) char lds[71168];   // ring 4x16KB | reL 4KB | tails
    float* reL   = (float*)(lds + 65536);   // 1024 f32
    float* zsqL  = (float*)(lds + 69632);   // 128 f32
    int*   idsL  = (int*)  (lds + 70144);   // 128 i32
    float* lossL = (float*)(lds + 70656);   // 128 f32

    const int tid = threadIdx.x;
    const int w   = tid >> 6;       // 0..3
    const int l   = tid & 63;
    const int lane15 = l & 15;
    const int lk     = l >> 4;
    const int r0  = blockIdx.x * 128;
    const int b   = r0 >> 12;
    const int t0  = r0 & 4095;
    const char* ehc = (const char*)eh;

    *(float4*)(reL + tid * 4) = *(const float4*)(re + tid * 4);

    // z A-fragments: 32 rows/wave (2 rowgroups); row = rg*16+lane15, k-quarter = lk.
    f16x8 ah[2][8];
    float zsq[2] = {0.f, 0.f};
    {
        const float* zw = z + (size_t)b * ZD * TT + t0 + w * 32 + lane15;
        #pragma unroll
        for (int rg = 0; rg < 2; ++rg) {
            const float* zr = zw + rg * 16;
            #pragma unroll
            for (int ks = 0; ks < 8; ++ks) {
                f16x8 h;
                #pragma unroll
                for (int j = 0; j < 8; ++j) {
                    float v = zr[(size_t)(ks * 32 + lk * 8 + j) * TT];
                    zsq[rg] = fmaf(v, v, zsq[rg]);
                    h[j] = (_Float16)v;
                }
                ah[rg][ks] = h;
            }
        }
    }
    #pragma unroll
    for (int rg = 0; rg < 2; ++rg) {
        zsq[rg] += __shfl_xor(zsq[rg], 16, 64);
        zsq[rg] += __shfl_xor(zsq[rg], 32, 64);
        if (l < 16) zsqL[w * 32 + rg * 16 + l] = zsq[rg];
    }

    float v1[8], v2[8];
    int   i1[8];
    #pragma unroll
    for (int s8 = 0; s8 < 8; ++s8) { v1[s8] = 3.4e38f; v2[s8] = 3.4e38f; i1[s8] = 0; }

    // drain A-loads + reL/zsqL ds ops so vmcnt counts only stage loads
    asm volatile("s_waitcnt vmcnt(0) lgkmcnt(0)" ::: "memory");
    stage_half4(ehc, lds,         0, w, l);
    stage_half4(ehc, lds + 16384, 1, w, l);
    stage_half4(ehc, lds + 32768, 2, w, l);

    // Phase h reads buf[h&3]; stage(h+3) (issued after the phase-h barrier) writes
    // buf[(h-1)&3], whose reads finished at that barrier. At the wait, stages h+1
    // and h+2 are outstanding (4 loads each) -> vmcnt(8) guarantees stage h landed.
    for (int h = 0; h < 30; ++h) {
        asm volatile("s_waitcnt vmcnt(8)" ::: "memory");
        __builtin_amdgcn_sched_barrier(0);
        __builtin_amdgcn_s_barrier();
        if (h < 29) stage_half4(ehc, lds + ((h + 3) & 3) * 16384, h + 3, w, l);
        compute_phase32(lds + (h & 3) * 16384, h, ah, reL, v1, v2, i1, lane15, lk);
    }
    asm volatile("s_waitcnt vmcnt(4)" ::: "memory");
    __builtin_amdgcn_sched_barrier(0);
    __builtin_amdgcn_s_barrier();
    compute_phase32(lds + (30 & 3) * 16384, 30, ah, reL, v1, v2, i1, lane15, lk);
    asm volatile("s_waitcnt vmcnt(0)" ::: "memory");
    __builtin_amdgcn_sched_barrier(0);
    __builtin_amdgcn_s_barrier();
    compute_phase32(lds + (31 & 3) * 16384, 31, ah, reL, v1, v2, i1, lane15, lk);

    // reduce across the 16 lanes holding different codes (same rows)
    #pragma unroll
    for (int off = 1; off < 16; off <<= 1) {
        #pragma unroll
        for (int s8 = 0; s8 < 8; ++s8) {
            float ov1 = __shfl_xor(v1[s8], off, 64);
            int   oi1 = __shfl_xor(i1[s8], off, 64);
            float ov2 = __shfl_xor(v2[s8], off, 64);
            float nv2 = fminf(fmaxf(v1[s8], ov1), fminf(v2[s8], ov2));
            if (ov1 < v1[s8] || (ov1 == v1[s8] && oi1 < i1[s8])) { v1[s8] = ov1; i1[s8] = oi1; }
            v2[s8] = nv2;
        }
    }
    if (lane15 == 0) {
        #pragma unroll
        for (int s8 = 0; s8 < 8; ++s8) {
            const int rg = s8 >> 2, rr = s8 & 3;
            const int row = w * 32 + rg * 16 + lk * 4 + rr;   // local row 0..127
            idsL[row] = i1[s8];
            const bool fl = (v2[s8] - v1[s8] < TAU);
            lossL[row] = fl ? zsqL[row] : (zsqL[row] + v1[s8]);
            atomicAdd(&hist[i1[s8]], 1.0f);
            if (fl) {
                int p = atomicAdd(cnt, 1);
                if (p < FLAGCAP) flags[p] = (r0 + row) | (i1[s8] << 16);
            }
        }
    }
    __syncthreads();

    // block loss reduce (threads 0..127)
    if (tid < 128) {
        float lv = lossL[tid];
        #pragma unroll
        for (int off = 32; off; off >>= 1) lv += __shfl_down(lv, off, 64);
        if (l == 0) { atomicAdd(scal + 0, lv); atomicAdd(scal + 1, lv); }
    }

    // out-write: wave w covers c in [64w, 64w+64), all 128 rows
    {
        const int c0 = w * 64;
        float* ob = out + (size_t)b * ZD * TT + t0;
        #pragma unroll
        for (int half = 0; half < 2; ++half) {
            const int tt = half * 64 + l;
            const int ii = idsL[tt];
            const float4* er4 = (const float4*)(emb + (size_t)ii * ZD + c0);
            #pragma unroll
            for (int c4 = 0; c4 < 16; ++c4) {
                float4 ev = er4[c4];
                float* o0 = ob + (size_t)(c0 + c4 * 4) * TT + tt;
                o0[0]      = ev.x;
                o0[TT]     = ev.y;
                o0[2 * TT] = ev.z;
                o0[3 * TT] = ev.w;
            }
        }
    }
}

// ---------------- fixup (blocks 0..127) + sparsity partials (blocks 128..255) ----------------
__global__ __launch_bounds__(256)
void vq_fixup_spar(const float* __restrict__ z, const float* __restrict__ emb,
                   const float* __restrict__ re, const int* __restrict__ cnt,
                   const int* __restrict__ flags, float* __restrict__ out,
                   float* __restrict__ scal, float* __restrict__ hist,
                   float* __restrict__ spar) {
    const int tid = threadIdx.x;
    const int w   = tid >> 6;
    const int lane = tid & 63;

    if (blockIdx.x >= 128) {
        // ---- sparsity: 8 rows/block, partial to spar[bid2] ----
        __shared__ __align__(16) float er[8][260];
        __shared__ float wmaxS[8][4];
        __shared__ float wsumS[8][4];
        __shared__ float shD[8];
        const int bid2 = blockIdx.x - 128;      // 0..127
        const int r0   = bid2 * 8;

        for (int i = tid; i < 8 * 256; i += 256) er[i >> 8][i & 255] = emb[(size_t)r0 * ZD + i];
        __syncthreads();

        float dots[4][8];
        #pragma unroll
        for (int cc = 0; cc < 4; ++cc) {
            const int c = cc * 256 + tid;
            const float4* ec = (const float4*)(emb + (size_t)c * ZD);
            float a[8] = {0.f,0.f,0.f,0.f,0.f,0.f,0.f,0.f};
            for (int k4 = 0; k4 < ZD / 4; ++k4) {
                float4 e4 = ec[k4];
                #pragma unroll
                for (int r = 0; r < 8; ++r) {
                    const float* a4 = &er[r][k4 * 4];
                    a[r] = fmaf(e4.x, a4[0], fmaf(e4.y, a4[1],
                           fmaf(e4.z, a4[2], fmaf(e4.w, a4[3], a[r]))));
                }
            }
            #pragma unroll
            for (int r = 0; r < 8; ++r) dots[cc][r] = a[r];
            const int gr = c - r0;
            if (gr >= 0 && gr < 8) shD[gr] = a[gr];
        }
        #pragma unroll
        for (int r = 0; r < 8; ++r) {
            float m = fmaxf(fmaxf(dots[0][r], dots[1][r]), fmaxf(dots[2][r], dots[3][r]));
            #pragma unroll
            for (int off = 32; off; off >>= 1) m = fmaxf(m, __shfl_xor(m, off, 64));
            if (lane == 0) wmaxS[r][w] = m;
        }
        __syncthreads();
        #pragma unroll
        for (int r = 0; r < 8; ++r) {
            const float M = fmaxf(fmaxf(wmaxS[r][0], wmaxS[r][1]),
                                  fmaxf(wmaxS[r][2], wmaxS[r][3]));
            float se = expf(dots[0][r] - M) + expf(dots[1][r] - M)
                     + expf(dots[2][r] - M) + expf(dots[3][r] - M);
            #pragma unroll
            for (int off = 32; off; off >>= 1) se += __shfl_xor(se, off, 64);
            if (lane == 0) wsumS[r][w] = se;
        }
        __syncthreads();
        if (tid == 0) {
            float acc = 0.f;
            #pragma unroll
            for (int r = 0; r < 8; ++r) {
                const float M = fmaxf(fmaxf(wmaxS[r][0], wmaxS[r][1]),
                                      fmaxf(wmaxS[r][2], wmaxS[r][3]));
                const float S = wsumS[r][0] + wsumS[r][1] + wsumS[r][2] + wsumS[r][3];
                acc += M + logf(S) - shD[r];
            }
            spar[bid2] = acc;
        }
        return;
    }

    // ---- fixup: exact fp32 rescore, 8 flagged rows per pass, 128 blocks ----
    __shared__ __align__(16) float zs[8][ZD];
    __shared__ u64 sb[4][8];
    __shared__ int nwS[8];
    __shared__ float addS;
    int n = *cnt;
    if (n > FLAGCAP) n = FLAGCAP;

    for (int base = blockIdx.x * 8; base < n; base += 128 * 8) {
        const int nr = (n - base < 8) ? (n - base) : 8;
        __syncthreads();
        for (int i = tid; i < nr * 256; i += 256) {
            const int r = i >> 8, k = i & 255;
            const int rowg = flags[base + r] & 0xFFFF;
            zs[r][k] = z[(size_t)(rowg >> 12) * ZD * TT + (size_t)k * TT + (rowg & 4095)];
        }
        __syncthreads();

        u64 best[8];
        #pragma unroll
        for (int r = 0; r < 8; ++r) best[r] = 0xFFFFFFFFFFFFFFFFull;

        for (int cc = 0; cc < 4; ++cc) {
            const int c = cc * 256 + tid;
            const float4* ec = (const float4*)(emb + (size_t)c * ZD);
            float a[8] = {0.f,0.f,0.f,0.f,0.f,0.f,0.f,0.f};
            for (int k4 = 0; k4 < ZD / 4; ++k4) {
                float4 e4 = ec[k4];
                #pragma unroll
                for (int r = 0; r < 8; ++r) {
                    const float* a4 = &zs[r][k4 * 4];
                    a[r] = fmaf(e4.x, a4[0], fmaf(e4.y, a4[1],
                           fmaf(e4.z, a4[2], fmaf(e4.w, a4[3], a[r]))));
                }
            }
            const float rc = re[c];
            #pragma unroll
            for (int r = 0; r < 8; ++r) {
                if (r < nr) {
                    float s = fmaf(-2.f, a[r], rc);
                    u64 pk = ((u64)flip32(s) << 32) | (u32)c;
                    if (pk < best[r]) best[r] = pk;
                }
            }
        }
        #pragma unroll
        for (int r = 0; r < 8; ++r) {
            if (r < nr) {
                u64 bv = best[r];
                #pragma unroll
                for (int off = 32; off; off >>= 1) {
                    u64 o = (u64)__shfl_xor((long long)bv, off, 64);
                    if (o < bv) bv = o;
                }
                if (lane == 0) sb[w][r] = bv;
            }
        }
        __syncthreads();
        if (tid == 0) addS = 0.f;
        __syncthreads();
        if (tid < nr) {
            u64 m = sb[0][tid];
            if (sb[1][tid] < m) m = sb[1][tid];
            if (sb[2][tid] < m) m = sb[2][tid];
            if (sb[3][tid] < m) m = sb[3][tid];
            const int nc  = (int)(u32)(m & 0xFFFFFFFFull);
            const float s = unflip32((u32)(m >> 32));
            const int old = (flags[base + tid] >> 16) & 1023;
            atomicAdd(&addS, s);
            if (nc != old) {
                atomicAdd(&hist[old], -1.0f);
                atomicAdd(&hist[nc], 1.0f);
                nwS[tid] = nc;
            } else nwS[tid] = -1;
        }
        __syncthreads();
        if (tid == 0) { atomicAdd(scal + 0, addS); atomicAdd(scal + 1, addS); }
        for (int r = 0; r < nr; ++r) {
            const int nw = nwS[r];
            if (nw >= 0) {
                const int rowg = flags[base + r] & 0xFFFF;
                out[(size_t)(rowg >> 12) * ZD * TT + (size_t)tid * TT + (rowg & 4095)]
                    = emb[(size_t)nw * ZD + tid];
            }
        }
    }
}

// ---------------- final: perplexity + sparsity partial sum ----------------
__global__ __launch_bounds__(256)
void vq_final_kernel(const float* __restrict__ hist, const float* __restrict__ spar,
                     float* __restrict__ scal) {
    __shared__ float red[256];
    const int tid = threadIdx.x;
    float s = 0.f;
    for (int j = tid; j < KC; j += 256) {
        float p = hist[j] * (1.0f / (float)NROWS);
        s -= p * logf(p + 1e-10f);
    }
    red[tid] = s;
    __syncthreads();
    for (int st = 128; st; st >>= 1) {
        if (tid < st) red[tid] += red[tid + st];
        __syncthreads();
    }
    if (tid == 0) scal[2] = expf(red[0]);
    __syncthreads();
    red[tid] = (tid < 128) ? spar[tid] : 0.f;
    __syncthreads();
    for (int st = 128; st; st >>= 1) {
        if (tid < st) red[tid] += red[tid + st];
        __syncthreads();
    }
    if (tid == 0) scal[3] = red[0] * (1.0f / (float)KC);
}

extern "C" void kernel_launch(void* const* d_in, const int* in_sizes, int n_in,
                              void* d_out, int out_size, void* d_ws, size_t ws_size,
                              hipStream_t stream) {
    const float* z   = (const float*)d_in[0];
    const float* emb = (const float*)d_in[1];
    float* out = (float*)d_out;
    const size_t NOUT = (size_t)BB * ZD * TT;    // 16777216
    float* scal = out + NOUT;                    // [qut, enc, perp, sparsity]

    float* re    = (float*)d_ws;                 // 1024 f32
    float* hist  = re + KC;                      // 1024 f32
    int*   cnt   = (int*)(hist + KC);            // 4 i32
    int*   flags = cnt + 4;                      // FLAGCAP i32
    float* spar  = (float*)(flags + FLAGCAP);    // 128 f32
    _Float16* eh = (_Float16*)(spar + 128);      // 1024*256 f16

    vq_prep_kernel<<<256, 256, 0, stream>>>(emb, eh, re, hist, cnt, scal);
    vq_argmin_mfma<<<NROWS / 128, 256, 0, stream>>>(z, eh, emb, re, out, scal, hist,
                                                    cnt, flags);
    vq_fixup_spar<<<256, 256, 0, stream>>>(z, emb, re, cnt, flags, out, scal, hist, spar);
    vq_final_kernel<<<1, 256, 0, stream>>>(hist, spar, scal);
}